// Round 1
// baseline (576.515 us; speedup 1.0000x reference)
//
#include <hip/hip_runtime.h>

#define NQ     12
#define DIM    4096
#define BATCH  4096
#define NGEN   2

// ---------------- compile-time GF(2) ring-permutation tables ----------------
// Basis index b: wire w <-> bit position p = 11 - w  (C-order flatten of (2,)*12).
// CNOT(c_pos, t_pos) state map: new[b] = old[m(b)], m(b) = b ^ (bit_c(b) << t). Linear over GF(2).
// Ring (wires): CNOT(0,1), CNOT(1,2), ..., CNOT(10,11), CNOT(11,0)
//   positions:  (11,10), (10,9), ..., (1,0), (0,11)
// Composite ring map R(b) = m1(m2(...m12(b))) (innermost = last gate).
constexpr unsigned cnot_map(unsigned b, int c, int t) {
  return b ^ (((b >> c) & 1u) << t);
}
constexpr unsigned ring_fwd(unsigned b) {
  b = cnot_map(b, 0, 11);                              // m12 applied to b first
  for (int y = 10; y >= 0; --y) b = cnot_map(b, 11 - y, 10 - y); // m11 ... m1
  return b;
}
constexpr unsigned ring_inv(unsigned b) {
  for (int y = 0; y <= 10; ++y) b = cnot_map(b, 11 - y, 10 - y); // m1 ... m11
  b = cnot_map(b, 0, 11);                              // m12
  return b;
}
constexpr unsigned pw (unsigned b, int k) { for (int r = 0; r < k; ++r) b = ring_fwd(b); return b; }
constexpr unsigned pwi(unsigned b, int k) { for (int r = 0; r < k; ++r) b = ring_inv(b); return b; }
constexpr int parity12(unsigned x) { int p = 0; for (int j = 0; j < 12; ++j) p ^= (x >> j) & 1; return p; }

struct QTables {
  unsigned short v[2][12];    // pairing vector: R^(li+1) e_p
  unsigned short c[2][12];    // selector mask:  row_p(R^-(li+1)); logical bit = parity(q & c)
  unsigned short Flo[64];     // final gather F = R^3, split low/high 6 bits
  unsigned short Fhi[64];
};
constexpr QTables make_tables() {
  QTables t{};
  for (int li = 0; li < 2; ++li)
    for (int y = 0; y < 12; ++y) {
      const int p = 11 - y;
      t.v[li][y] = (unsigned short)pw(1u << p, li + 1);
      unsigned cm = 0;
      for (int j = 0; j < 12; ++j)
        cm |= (unsigned)((pwi(1u << j, li + 1) >> p) & 1u) << j;
      t.c[li][y] = (unsigned short)cm;
    }
  for (int i = 0; i < 64; ++i) {
    t.Flo[i] = (unsigned short)pw((unsigned)i, 3);
    t.Fhi[i] = (unsigned short)pw((unsigned)i << 6, 3);
  }
  return t;
}
constexpr QTables h_tb = make_tables();
constexpr bool check_tables() {
  // each pair (q, q^v) must contain exactly one parity-0 element
  for (int li = 0; li < 2; ++li)
    for (int y = 0; y < 12; ++y)
      if (parity12((unsigned)h_tb.v[li][y] & (unsigned)h_tb.c[li][y]) != 1) return false;
  // inverse sanity
  if (ring_inv(ring_fwd(0xABCu)) != 0xABCu) return false;
  if (ring_inv(ring_fwd(0x555u)) != 0x555u) return false;
  if (ring_fwd(ring_inv(0xF0Fu)) != 0xF0Fu) return false;
  return true;
}
static_assert(check_tables(), "GF(2) ring tables inconsistent");
__constant__ QTables TB = make_tables();

// ---------------- complex helpers ----------------
__device__ __forceinline__ float2 cmul(float2 a, float2 b) {
  return make_float2(a.x * b.x - a.y * b.y, a.x * b.y + a.y * b.x);
}
__device__ __forceinline__ float2 cadd(float2 a, float2 b) {
  return make_float2(a.x + b.x, a.y + b.y);
}
__device__ __forceinline__ void mat2mul(const float2* A, const float2* B, float2* C) {
  C[0] = cadd(cmul(A[0], B[0]), cmul(A[1], B[2]));
  C[1] = cadd(cmul(A[0], B[1]), cmul(A[1], B[3]));
  C[2] = cadd(cmul(A[2], B[0]), cmul(A[3], B[2]));
  C[3] = cadd(cmul(A[2], B[1]), cmul(A[3], B[3]));
}
// U = RY(c) * RX(b) * RZ(a)   (RZ applied first in the circuit)
__device__ __forceinline__ void fusedU(float a, float b, float c, float2* U) {
  float sa, ca, sb, cb, sc, cc;
  sincosf(a * 0.5f, &sa, &ca);
  sincosf(b * 0.5f, &sb, &cb);
  sincosf(c * 0.5f, &sc, &cc);
  float2 RZ[4] = { {ca, -sa}, {0.f, 0.f}, {0.f, 0.f}, {ca, sa} };
  float2 RX[4] = { {cb, 0.f}, {0.f, -sb}, {0.f, -sb}, {cb, 0.f} };
  float2 RY[4] = { {cc, 0.f}, {-sc, 0.f}, {sc, 0.f}, {cc, 0.f} };
  float2 M[4];
  mat2mul(RX, RZ, M);
  mat2mul(RY, M, U);
}

// ---------------- circuit kernel: one block = one (sample, generator) ----------------
__global__ __launch_bounds__(256) void qcirc_kernel(const float* __restrict__ x,
                                                    const float* __restrict__ qp,
                                                    float* __restrict__ out) {
  __shared__ float2 st[DIM];        // 32 KB state
  __shared__ float2 Umat[24][4];    // fused gates, layers 1..2
  __shared__ float2 vq[NQ][2];      // per-qubit initial 2-vectors (layer 0 folded)

  const int tid = threadIdx.x;
  const int s = blockIdx.x >> 1;
  const int g = blockIdx.x & 1;

  if (tid < 24) {                   // layer-1/2 fused gates
    const int li = tid / 12, y = tid % 12;
    const float* w = qp + g * 108 + (li + 1) * 36 + 3 * y;
    fusedU(w[0], w[1], w[2], Umat[tid]);
  } else if (tid >= 64 && tid < 64 + NQ) {   // layer-0 product-state vectors (other wave)
    const int j = tid - 64;
    const float* w = qp + g * 108 + 3 * j;
    float2 U0[4];
    fusedU(w[0], w[1], w[2], U0);
    float cx, sx;
    sincosf(x[s * NQ + j] * 0.5f, &sx, &cx);
    vq[j][0] = make_float2(U0[0].x * cx + U0[1].x * sx, U0[0].y * cx + U0[1].y * sx);
    vq[j][1] = make_float2(U0[2].x * cx + U0[3].x * sx, U0[2].y * cx + U0[3].y * sx);
  }
  __syncthreads();

  // build product state: entry e = r*256 + tid; bit p of e selects vq[11-p][.]
  float2 low = vq[11][tid & 1];
  #pragma unroll
  for (int p = 1; p < 8; ++p) low = cmul(low, vq[11 - p][(tid >> p) & 1]);
  #pragma unroll
  for (int r = 0; r < 16; ++r) {
    float2 h = vq[3][r & 1];
    h = cmul(h, vq[2][(r >> 1) & 1]);
    h = cmul(h, vq[1][(r >> 2) & 1]);
    h = cmul(h, vq[0][(r >> 3) & 1]);
    st[r * 256 + tid] = cmul(low, h);
  }

  // 24 fused gates with ring permutations folded into (v, c) tables
  for (int li = 0; li < 2; ++li) {
    for (int y = 0; y < 12; ++y) {
      __syncthreads();
      const unsigned vv = TB.v[li][y];
      const unsigned cm = TB.c[li][y];
      const int jl = __ffs((int)cm) - 1;
      const float2 u00 = Umat[li * 12 + y][0];
      const float2 u01 = Umat[li * 12 + y][1];
      const float2 u10 = Umat[li * 12 + y][2];
      const float2 u11 = Umat[li * 12 + y][3];
      #pragma unroll
      for (int k = 0; k < 8; ++k) {
        // balanced bijection i -> parity-0 representative q0
        unsigned i = (unsigned)(k * 256 + tid);
        unsigned q0 = ((i >> jl) << (jl + 1)) | (i & ((1u << jl) - 1u));
        q0 ^= (unsigned)(__popc(q0 & cm) & 1) << jl;
        const unsigned q1 = q0 ^ vv;
        const float2 s0 = st[q0];
        const float2 s1 = st[q1];
        st[q0] = cadd(cmul(u00, s0), cmul(u01, s1));
        st[q1] = cadd(cmul(u10, s0), cmul(u11, s1));
      }
    }
  }
  __syncthreads();

  // output gather with final ring^3 folded: out[l] = |st[F(l)]|^2
  float* ob = out + (size_t)s * (NGEN * DIM) + (size_t)g * DIM;
  #pragma unroll
  for (int k = 0; k < 16; ++k) {
    const unsigned l = (unsigned)(k * 256 + tid);
    const unsigned q = (unsigned)TB.Flo[l & 63] ^ (unsigned)TB.Fhi[l >> 6];
    const float2 a = st[q];
    ob[l] = a.x * a.x + a.y * a.y;
  }
}

// ---------------- linear kernel: converted_x = (x @ W^T + b) * 5 ----------------
__global__ __launch_bounds__(256) void linear_kernel(const float* __restrict__ x,
                                                     const float* __restrict__ w,
                                                     const float* __restrict__ b,
                                                     float* __restrict__ out2) {
  const int tid = threadIdx.x;
  const int s = blockIdx.x >> 2;                    // 4 blocks per sample
  const int d0 = ((blockIdx.x & 3) * 1024) + tid * 4;

  float xv[NQ];
  #pragma unroll
  for (int j = 0; j < NQ; ++j) xv[j] = x[s * NQ + j];

  float4 res;
  float* rp = &res.x;
  #pragma unroll
  for (int dd = 0; dd < 4; ++dd) {
    const int d = d0 + dd;
    float acc = b[d];
    #pragma unroll
    for (int j = 0; j < NQ; ++j) acc = fmaf(xv[j], w[d * NQ + j], acc);
    rp[dd] = acc * 5.0f;
  }
  *(float4*)&out2[(size_t)s * DIM + d0] = res;
}

extern "C" void kernel_launch(void* const* d_in, const int* in_sizes, int n_in,
                              void* d_out, int out_size, void* d_ws, size_t ws_size,
                              hipStream_t stream) {
  const float* x    = (const float*)d_in[0];
  const float* qp   = (const float*)d_in[1];
  const float* linw = (const float*)d_in[2];
  const float* linb = (const float*)d_in[3];
  float* out = (float*)d_out;

  qcirc_kernel<<<BATCH * NGEN, 256, 0, stream>>>(x, qp, out);
  linear_kernel<<<BATCH * 4, 256, 0, stream>>>(x, linw, linb,
                                               out + (size_t)BATCH * NGEN * DIM);
}

// Round 2
// 456.541 us; speedup vs baseline: 1.2628x; 1.2628x over previous
//
#include <hip/hip_runtime.h>

#define NQ     12
#define DIM    4096
#define BATCH  4096
#define NGEN   2

// ---------------- compile-time GF(2) ring-permutation tables ----------------
// Basis index b: wire w <-> bit position p = 11 - w  (C-order flatten of (2,)*12).
constexpr unsigned cnot_map(unsigned b, int c, int t) {
  return b ^ (((b >> c) & 1u) << t);
}
constexpr unsigned ring_fwd(unsigned b) {
  b = cnot_map(b, 0, 11);
  for (int y = 10; y >= 0; --y) b = cnot_map(b, 11 - y, 10 - y);
  return b;
}
constexpr unsigned ring_inv(unsigned b) {
  for (int y = 0; y <= 10; ++y) b = cnot_map(b, 11 - y, 10 - y);
  b = cnot_map(b, 0, 11);
  return b;
}
constexpr unsigned pw (unsigned b, int k) { for (int r = 0; r < k; ++r) b = ring_fwd(b); return b; }
constexpr unsigned pwi(unsigned b, int k) { for (int r = 0; r < k; ++r) b = ring_inv(b); return b; }
constexpr int parity12(unsigned x) { int p = 0; for (int j = 0; j < 12; ++j) p ^= (x >> j) & 1; return p; }

struct QT {
  unsigned short v[2][12];    // pairing vector: R^(li+1) e_p
  unsigned short c[2][12];    // selector mask:  row_p(R^-(li+1))
};
constexpr QT make_qt() {
  QT t{};
  for (int li = 0; li < 2; ++li)
    for (int y = 0; y < 12; ++y) {
      const int p = 11 - y;
      t.v[li][y] = (unsigned short)pw(1u << p, li + 1);
      unsigned cm = 0;
      for (int j = 0; j < 12; ++j)
        cm |= (unsigned)((pwi(1u << j, li + 1) >> p) & 1u) << j;
      t.c[li][y] = (unsigned short)cm;
    }
  return t;
}
constexpr QT qt = make_qt();

// Orthogonality: parity(v_a & c_b) = delta_ab within a layer (enables the
// uniform-orientation trick: logical bit of tile entry j for gate b = j_b ^ pb).
constexpr bool ortho_ok() {
  for (int li = 0; li < 2; ++li)
    for (int a = 0; a < 12; ++a)
      for (int b = 0; b < 12; ++b)
        if (parity12((unsigned)qt.v[li][a] & (unsigned)qt.c[li][b]) != (a == b ? 1 : 0))
          return false;
  if (ring_inv(ring_fwd(0xABCu)) != 0xABCu) return false;
  return true;
}
static_assert(ortho_ok(), "GF(2) orthogonality violated");

// Fixed LDS layout swizzle (linear, bijective): spreads high index bits into banks.
constexpr unsigned A12(unsigned q) { return (q ^ (q >> 4) ^ (q >> 8)) & 0xFFFu; }

constexpr int msb12(unsigned x) { int m = -1; for (int i = 0; i < 12; ++i) if ((x >> i) & 1) m = i; return m; }
constexpr bool bins(unsigned* byMsb, unsigned x) {   // Gaussian insert, true if independent
  while (x) { int m = msb12(x); if (!byMsb[m]) { byMsb[m] = x; return true; } x ^= byMsb[m]; }
  return false;
}

// 6 passes (2 layers x 3 groups of 4 commuting gates). Per pass each thread owns
// one coset of span{v_b}: 16 entries e[j] = st[A(tbase ^ G(j))].
struct GTab {
  unsigned short lut[6][256];   // low12: A(tbase(tid)); bits12..15: pb_b = parity(tbase & c_b)
  unsigned short gv[6][16];     // A(G(j)), G(j) = XOR of v_b over set bits of j
  unsigned short sflo[256];     // A(R^3(tid))     (output gather, low 8 bits)
  unsigned short sfhi[16];      // A(R^3(k << 8))  (output gather, high 4 bits)
  unsigned char ok;
};
constexpr GTab make_gtab() {
  GTab t{};
  bool good = true;
  for (int li = 0; li < 2; ++li)
    for (int gi = 0; gi < 3; ++gi) {
      const int gid = li * 3 + gi;
      unsigned v[4], cm[4];
      for (int b = 0; b < 4; ++b) { v[b] = qt.v[li][gi * 4 + b]; cm[b] = qt.c[li][gi * 4 + b]; }
      // transversal: greedily extend {v} with unit vectors, preferring LOW bit
      // positions (those drive LDS bank index) for low tid bits.
      unsigned byMsb[12] = {};
      for (int b = 0; b < 4; ++b) if (!bins(byMsb, v[b])) good = false;
      int Tpos[8] = {}; int c = 0;
      for (int cand = 0; cand < 12 && c < 8; ++cand)
        if (bins(byMsb, 1u << cand)) Tpos[c++] = cand;
      if (c != 8) good = false;
      for (int tid = 0; tid < 256; ++tid) {
        unsigned q = 0;
        for (int cc = 0; cc < 8; ++cc) if ((tid >> cc) & 1) q ^= 1u << Tpos[cc];
        unsigned pb = 0;
        for (int b = 0; b < 4; ++b) pb |= (unsigned)parity12(q & cm[b]) << b;
        t.lut[gid][tid] = (unsigned short)(A12(q) | (pb << 12));
      }
      for (int j = 0; j < 16; ++j) {
        unsigned g = 0;
        for (int b = 0; b < 4; ++b) if ((j >> b) & 1) g ^= v[b];
        t.gv[gid][j] = (unsigned short)A12(g);
      }
      bool seen[4096] = {};
      for (int tid = 0; tid < 256; ++tid)
        for (int j = 0; j < 16; ++j) {
          unsigned idx = (unsigned)(t.lut[gid][tid] & 0xFFF) ^ (unsigned)t.gv[gid][j];
          if (seen[idx]) good = false;
          seen[idx] = true;
        }
    }
  for (int tid = 0; tid < 256; ++tid) t.sflo[tid] = (unsigned short)A12(pw((unsigned)tid, 3));
  for (int k = 0; k < 16; ++k)       t.sfhi[k]   = (unsigned short)A12(pw((unsigned)k << 8, 3));
  t.ok = good ? 1 : 0;
  return t;
}
constexpr GTab h_gtab = make_gtab();
static_assert(h_gtab.ok == 1, "group tables inconsistent");
__constant__ GTab d_gtab = make_gtab();

// ---------------- complex helpers ----------------
__device__ __forceinline__ float2 cmul(float2 a, float2 b) {
  return make_float2(a.x * b.x - a.y * b.y, a.x * b.y + a.y * b.x);
}
__device__ __forceinline__ float2 cadd(float2 a, float2 b) {
  return make_float2(a.x + b.x, a.y + b.y);
}
__device__ __forceinline__ void mat2mul(const float2* A, const float2* B, float2* C) {
  C[0] = cadd(cmul(A[0], B[0]), cmul(A[1], B[2]));
  C[1] = cadd(cmul(A[0], B[1]), cmul(A[1], B[3]));
  C[2] = cadd(cmul(A[2], B[0]), cmul(A[3], B[2]));
  C[3] = cadd(cmul(A[2], B[1]), cmul(A[3], B[3]));
}
// U = RY(c)*RX(b)*RZ(a); U is SU(2): u11 = conj(u00), u10 = -conj(u01)
__device__ __forceinline__ void fusedU(float a, float b, float c, float2* U) {
  float sa, ca, sb, cb, sc, cc;
  sincosf(a * 0.5f, &sa, &ca);
  sincosf(b * 0.5f, &sb, &cb);
  sincosf(c * 0.5f, &sc, &cc);
  float2 RZ[4] = { {ca, -sa}, {0.f, 0.f}, {0.f, 0.f}, {ca, sa} };
  float2 RX[4] = { {cb, 0.f}, {0.f, -sb}, {0.f, -sb}, {cb, 0.f} };
  float2 RY[4] = { {cc, 0.f}, {-sc, 0.f}, {sc, 0.f}, {cc, 0.f} };
  float2 M[4];
  mat2mul(RX, RZ, M);
  mat2mul(RY, M, U);
}

// ---------------- circuit kernel: one block = one (sample, generator) ----------------
__global__ __launch_bounds__(256) void qcirc_kernel(const float* __restrict__ x,
                                                    const float* __restrict__ qp,
                                                    float* __restrict__ out) {
  __shared__ float2 st[DIM];        // 32 KB state, stored at swizzled index A(q)
  __shared__ float2 gAB[24][2];     // (a,b) = (u00,u01) per fused gate, layers 1..2
  __shared__ float2 vq[NQ][2];      // per-qubit initial 2-vectors (layer 0 folded)

  const int tid = threadIdx.x;
  const int s = blockIdx.x >> 1;
  const int g = blockIdx.x & 1;

  if (tid < 24) {
    const int li = tid / 12, y = tid % 12;
    const float* w = qp + g * 108 + (li + 1) * 36 + 3 * y;
    float2 U[4];
    fusedU(w[0], w[1], w[2], U);
    gAB[tid][0] = U[0];
    gAB[tid][1] = U[1];
  } else if (tid >= 64 && tid < 64 + NQ) {
    const int j = tid - 64;
    const float* w = qp + g * 108 + 3 * j;
    float2 U0[4];
    fusedU(w[0], w[1], w[2], U0);
    float cx, sx;
    sincosf(x[s * NQ + j] * 0.5f, &sx, &cx);
    vq[j][0] = make_float2(U0[0].x * cx + U0[1].x * sx, U0[0].y * cx + U0[1].y * sx);
    vq[j][1] = make_float2(U0[2].x * cx + U0[3].x * sx, U0[2].y * cx + U0[3].y * sx);
  }
  __syncthreads();

  // product state (layer 0 folded): entry e = r*256+tid at A(e) = (r*0x111) ^ tid ^ (tid>>4)
  {
    const unsigned bt = (unsigned)tid ^ ((unsigned)tid >> 4);
    float2 low = vq[11][tid & 1];
    #pragma unroll
    for (int p = 1; p < 8; ++p) low = cmul(low, vq[11 - p][(tid >> p) & 1]);
    #pragma unroll
    for (int r = 0; r < 16; ++r) {
      float2 h = vq[3][r & 1];
      h = cmul(h, vq[2][(r >> 1) & 1]);
      h = cmul(h, vq[1][(r >> 2) & 1]);
      h = cmul(h, vq[0][(r >> 3) & 1]);
      st[(r * 0x111) ^ bt] = cmul(low, h);
    }
  }

  // 6 passes of 4 commuting gates applied in-register on a 16-entry coset tile
  for (int gid = 0; gid < 6; ++gid) {
    __syncthreads();
    const unsigned L  = d_gtab.lut[gid][tid];
    const unsigned tb = L & 0xFFFu;
    const unsigned pb = L >> 12;
    const unsigned short* gvp = d_gtab.gv[gid];

    float2 e[16];
    #pragma unroll
    for (int j = 0; j < 16; ++j) e[j] = st[tb ^ gvp[j]];

    const int gbase = (gid / 3) * 12 + (gid % 3) * 4;
    float2 ca[4], cb[4];
    #pragma unroll
    for (int b = 0; b < 4; ++b) { ca[b] = gAB[gbase + b][0]; cb[b] = gAB[gbase + b][1]; }

    #pragma unroll
    for (int b = 0; b < 4; ++b) {
      // orientation fold: pb_b=1 swaps roles <=> (A,B) := (conj a, -conj b)
      const unsigned sgn = ((pb >> b) & 1u) << 31;
      const float Ax = ca[b].x;
      const float Ay = __uint_as_float(__float_as_uint(ca[b].y) ^ sgn);
      const float Bx = __uint_as_float(__float_as_uint(cb[b].x) ^ sgn);
      const float By = cb[b].y;
      #pragma unroll
      for (int j0 = 0; j0 < 16; ++j0) {
        if (j0 & (1 << b)) continue;
        const int j1 = j0 | (1 << b);
        const float2 s0 = e[j0], s1 = e[j1];
        e[j0].x =  Ax * s0.x - Ay * s0.y + Bx * s1.x - By * s1.y;
        e[j0].y =  Ax * s0.y + Ay * s0.x + Bx * s1.y + By * s1.x;
        e[j1].x = -Bx * s0.x - By * s0.y + Ax * s1.x + Ay * s1.y;
        e[j1].y = -Bx * s0.y + By * s0.x + Ax * s1.y - Ay * s1.x;
      }
    }
    #pragma unroll
    for (int j = 0; j < 16; ++j) st[tb ^ gvp[j]] = e[j];
  }
  __syncthreads();

  // output gather with final ring^3 folded into A-composed tables
  float* ob = out + (size_t)s * (NGEN * DIM) + (size_t)g * DIM;
  const unsigned lo = d_gtab.sflo[tid];
  #pragma unroll
  for (int k = 0; k < 16; ++k) {
    const float2 a = st[lo ^ d_gtab.sfhi[k]];
    ob[k * 256 + tid] = a.x * a.x + a.y * a.y;
  }
}

// ---------------- linear kernel: converted_x = (x @ W^T + b) * 5 ----------------
#define SPB 32   // samples per block: W rows stay in registers, reused 32x
__global__ __launch_bounds__(256) void linear_kernel(const float* __restrict__ x,
                                                     const float* __restrict__ w,
                                                     const float* __restrict__ bb,
                                                     float* __restrict__ out2) {
  __shared__ float xs[SPB * NQ];
  const int tid = threadIdx.x;
  const int d0 = (blockIdx.x & 3) * 1024 + tid * 4;
  const int s0 = (blockIdx.x >> 2) * SPB;

  if (tid < SPB * NQ / 4)
    ((float4*)xs)[tid] = ((const float4*)(x + (size_t)s0 * NQ))[tid];

  float wr[4][NQ];
  float b4[4];
  #pragma unroll
  for (int dd = 0; dd < 4; ++dd) {
    #pragma unroll
    for (int jj = 0; jj < 3; ++jj)
      *(float4*)&wr[dd][jj * 4] = *(const float4*)&w[(size_t)(d0 + dd) * NQ + jj * 4];
    b4[dd] = bb[d0 + dd];
  }
  __syncthreads();

  for (int s = 0; s < SPB; ++s) {
    float4 r;
    float* rp = &r.x;
    #pragma unroll
    for (int dd = 0; dd < 4; ++dd) {
      float acc = b4[dd];
      #pragma unroll
      for (int j = 0; j < NQ; ++j) acc = fmaf(xs[s * NQ + j], wr[dd][j], acc);
      rp[dd] = acc * 5.0f;
    }
    *(float4*)&out2[(size_t)(s0 + s) * DIM + d0] = r;
  }
}

extern "C" void kernel_launch(void* const* d_in, const int* in_sizes, int n_in,
                              void* d_out, int out_size, void* d_ws, size_t ws_size,
                              hipStream_t stream) {
  const float* x    = (const float*)d_in[0];
  const float* qp   = (const float*)d_in[1];
  const float* linw = (const float*)d_in[2];
  const float* linb = (const float*)d_in[3];
  float* out = (float*)d_out;

  qcirc_kernel<<<BATCH * NGEN, 256, 0, stream>>>(x, qp, out);
  linear_kernel<<<(BATCH / SPB) * 4, 256, 0, stream>>>(x, linw, linb,
                                                       out + (size_t)BATCH * NGEN * DIM);
}

// Round 3
// 343.103 us; speedup vs baseline: 1.6803x; 1.3306x over previous
//
#include <hip/hip_runtime.h>

#define NQ     12
#define DIM    4096
#define BATCH  4096
#define NGEN   2

typedef float f32x2 __attribute__((ext_vector_type(2)));

// ---------------- compile-time GF(2) ring-permutation tables ----------------
// Basis index b: wire w <-> bit position p = 11 - w  (C-order flatten of (2,)*12).
constexpr unsigned cnot_map(unsigned b, int c, int t) {
  return b ^ (((b >> c) & 1u) << t);
}
constexpr unsigned ring_fwd(unsigned b) {
  b = cnot_map(b, 0, 11);
  for (int y = 10; y >= 0; --y) b = cnot_map(b, 11 - y, 10 - y);
  return b;
}
constexpr unsigned ring_inv(unsigned b) {
  for (int y = 0; y <= 10; ++y) b = cnot_map(b, 11 - y, 10 - y);
  b = cnot_map(b, 0, 11);
  return b;
}
constexpr unsigned pw (unsigned b, int k) { for (int r = 0; r < k; ++r) b = ring_fwd(b); return b; }
constexpr unsigned pwi(unsigned b, int k) { for (int r = 0; r < k; ++r) b = ring_inv(b); return b; }
constexpr int parity12(unsigned x) { int p = 0; for (int j = 0; j < 12; ++j) p ^= (x >> j) & 1; return p; }

struct QT {
  unsigned short v[2][12];    // pairing vector: R^(li+1) e_p
  unsigned short c[2][12];    // selector mask:  row_p(R^-(li+1))
};
constexpr QT make_qt() {
  QT t{};
  for (int li = 0; li < 2; ++li)
    for (int y = 0; y < 12; ++y) {
      const int p = 11 - y;
      t.v[li][y] = (unsigned short)pw(1u << p, li + 1);
      unsigned cm = 0;
      for (int j = 0; j < 12; ++j)
        cm |= (unsigned)((pwi(1u << j, li + 1) >> p) & 1u) << j;
      t.c[li][y] = (unsigned short)cm;
    }
  return t;
}
constexpr QT qt = make_qt();

// parity(v_a & c_b) = delta_ab within a layer -> uniform per-thread orientation.
constexpr bool ortho_ok() {
  for (int li = 0; li < 2; ++li)
    for (int a = 0; a < 12; ++a)
      for (int b = 0; b < 12; ++b)
        if (parity12((unsigned)qt.v[li][a] & (unsigned)qt.c[li][b]) != (a == b ? 1 : 0))
          return false;
  if (ring_inv(ring_fwd(0xABCu)) != 0xABCu) return false;
  return true;
}
static_assert(ortho_ok(), "GF(2) orthogonality violated");

// Fixed LDS layout swizzle (linear, bijective).
constexpr unsigned A12(unsigned q) { return (q ^ (q >> 4) ^ (q >> 8)) & 0xFFFu; }

constexpr int msb12(unsigned x) { int m = -1; for (int i = 0; i < 12; ++i) if ((x >> i) & 1) m = i; return m; }
constexpr bool bins(unsigned* byMsb, unsigned x) {
  while (x) { int m = msb12(x); if (!byMsb[m]) { byMsb[m] = x; return true; } x ^= byMsb[m]; }
  return false;
}

// 6 passes (2 layers x 3 groups of 4 commuting gates).
struct GTab {
  unsigned lut[6][256];         // (pb << 16) | (A12(tbase) << 3)   [byte offset]
  unsigned short gv[6][16];     // A12(G(j)); used as constexpr immediates, <<3 at use
  unsigned short sflo[256];     // A12(R^3(tid))
  unsigned short sfhi[16];      // A12(R^3(k << 8))
  unsigned char ok;
};
constexpr GTab make_gtab() {
  GTab t{};
  bool good = true;
  for (int li = 0; li < 2; ++li)
    for (int gi = 0; gi < 3; ++gi) {
      const int gid = li * 3 + gi;
      unsigned v[4], cm[4];
      for (int b = 0; b < 4; ++b) { v[b] = qt.v[li][gi * 4 + b]; cm[b] = qt.c[li][gi * 4 + b]; }
      unsigned byMsb[12] = {};
      for (int b = 0; b < 4; ++b) if (!bins(byMsb, v[b])) good = false;
      int Tpos[8] = {}; int c = 0;
      for (int cand = 0; cand < 12 && c < 8; ++cand)
        if (bins(byMsb, 1u << cand)) Tpos[c++] = cand;
      if (c != 8) good = false;
      for (int tid = 0; tid < 256; ++tid) {
        unsigned q = 0;
        for (int cc = 0; cc < 8; ++cc) if ((tid >> cc) & 1) q ^= 1u << Tpos[cc];
        unsigned pb = 0;
        for (int b = 0; b < 4; ++b) pb |= (unsigned)parity12(q & cm[b]) << b;
        t.lut[gid][tid] = (pb << 16) | (A12(q) << 3);
      }
      for (int j = 0; j < 16; ++j) {
        unsigned g = 0;
        for (int b = 0; b < 4; ++b) if ((j >> b) & 1) g ^= v[b];
        t.gv[gid][j] = (unsigned short)A12(g);
      }
      bool seen[4096] = {};
      for (int tid = 0; tid < 256; ++tid)
        for (int j = 0; j < 16; ++j) {
          unsigned idx = ((t.lut[gid][tid] & 0xFFFFu) >> 3) ^ (unsigned)t.gv[gid][j];
          if (idx >= 4096 || seen[idx]) good = false;
          seen[idx] = true;
        }
    }
  for (int tid = 0; tid < 256; ++tid) t.sflo[tid] = (unsigned short)A12(pw((unsigned)tid, 3));
  for (int k = 0; k < 16; ++k)       t.sfhi[k]   = (unsigned short)A12(pw((unsigned)k << 8, 3));
  t.ok = good ? 1 : 0;
  return t;
}
constexpr GTab h_gtab = make_gtab();
static_assert(h_gtab.ok == 1, "group tables inconsistent");
__constant__ GTab d_gtab = make_gtab();

// ---------------- scalar complex helpers (setup only) ----------------
__device__ __forceinline__ float2 cmuls(float2 a, float2 b) {
  return make_float2(a.x * b.x - a.y * b.y, a.x * b.y + a.y * b.x);
}
__device__ __forceinline__ float2 cadds(float2 a, float2 b) {
  return make_float2(a.x + b.x, a.y + b.y);
}
__device__ __forceinline__ void mat2mul(const float2* A, const float2* B, float2* C) {
  C[0] = cadds(cmuls(A[0], B[0]), cmuls(A[1], B[2]));
  C[1] = cadds(cmuls(A[0], B[1]), cmuls(A[1], B[3]));
  C[2] = cadds(cmuls(A[2], B[0]), cmuls(A[3], B[2]));
  C[3] = cadds(cmuls(A[2], B[1]), cmuls(A[3], B[3]));
}
// U = RY(c)*RX(b)*RZ(a); SU(2): u11 = conj(u00), u10 = -conj(u01)
__device__ __forceinline__ void fusedU(float a, float b, float c, float2* U) {
  float sa, ca, sb, cb, sc, cc;
  sincosf(a * 0.5f, &sa, &ca);
  sincosf(b * 0.5f, &sb, &cb);
  sincosf(c * 0.5f, &sc, &cc);
  float2 RZ[4] = { {ca, -sa}, {0.f, 0.f}, {0.f, 0.f}, {ca, sa} };
  float2 RX[4] = { {cb, 0.f}, {0.f, -sb}, {0.f, -sb}, {cb, 0.f} };
  float2 RY[4] = { {cc, 0.f}, {-sc, 0.f}, {sc, 0.f}, {cc, 0.f} };
  float2 M[4];
  mat2mul(RX, RZ, M);
  mat2mul(RY, M, U);
}

// packed complex multiply: 2 v_pk ops
__device__ __forceinline__ f32x2 pcmul(f32x2 a, f32x2 b) {
  return (f32x2){a.x, a.x} * b + (f32x2){-a.y, a.y} * (f32x2){b.y, b.x};
}
__device__ __forceinline__ float xorf(float f, unsigned m) {
  return __uint_as_float(__float_as_uint(f) ^ m);
}

// ---------------- one pass: 4 commuting gates on a 16-entry coset tile ----------------
template<int GID>
__device__ __forceinline__ void do_pass(f32x2* st, const f32x2 (*gAB)[2], int tid) {
  const unsigned L   = d_gtab.lut[GID][tid];
  const unsigned tbB = L & 0xFFFFu;   // byte offset of coset base (A12-swizzled, <<3)
  const unsigned pb  = L >> 16;       // orientation bits for the 4 gates
  char* stb = (char*)st;

  f32x2 e[16];
  #pragma unroll
  for (int j = 0; j < 16; ++j)
    e[j] = *(const f32x2*)(stb + (tbB ^ ((unsigned)h_gtab.gv[GID][j] << 3)));

  constexpr int gbase = (GID / 3) * 12 + (GID % 3) * 4;
  #pragma unroll
  for (int b = 0; b < 4; ++b) {
    const f32x2 ga = gAB[gbase + b][0];   // u00
    const f32x2 gb = gAB[gbase + b][1];   // u01
    const unsigned sg = ((pb >> b) & 1u) << 31;
    const float ax = ga.x;
    const float ay = xorf(ga.y, sg);      // orientation folds into sign of Ay, Bx
    const float bx = xorf(gb.x, sg);
    const float by = gb.y;
    const f32x2 P1 = {ax, ax};
    const f32x2 P2 = {-ay, ay};
    const f32x2 P3 = {bx, bx};
    const f32x2 P4 = {-by, by};
    #pragma unroll
    for (int j0 = 0; j0 < 16; ++j0) {
      if (j0 & (1 << b)) continue;
      const int j1 = j0 | (1 << b);
      const f32x2 s0 = e[j0], s1 = e[j1];
      const f32x2 w0 = {s0.y, s0.x}, w1 = {s1.y, s1.x};
      e[j0] = P1 * s0 + P2 * w0 + P3 * s1 + P4 * w1;
      e[j1] = P1 * s1 - P2 * w1 - P3 * s0 + P4 * w0;
    }
  }
  #pragma unroll
  for (int j = 0; j < 16; ++j)
    *(f32x2*)(stb + (tbB ^ ((unsigned)h_gtab.gv[GID][j] << 3))) = e[j];
}

// ---------------- circuit kernel: one block = one (sample, generator) ----------------
__global__ __launch_bounds__(256, 4) void qcirc_kernel(const float* __restrict__ x,
                                                       const float* __restrict__ qp,
                                                       float* __restrict__ out) {
  __shared__ f32x2 st[DIM];         // 32 KB state at swizzled index A12(q)
  __shared__ f32x2 gAB[24][2];      // (u00,u01) per fused gate, layers 1..2
  __shared__ f32x2 vq[NQ][2];       // per-qubit initial 2-vectors (layer 0 folded)

  const int tid = threadIdx.x;
  const int s = blockIdx.x >> 1;
  const int g = blockIdx.x & 1;

  if (tid < 24) {
    const int li = tid / 12, y = tid % 12;
    const float* w = qp + g * 108 + (li + 1) * 36 + 3 * y;
    float2 U[4];
    fusedU(w[0], w[1], w[2], U);
    gAB[tid][0] = (f32x2){U[0].x, U[0].y};
    gAB[tid][1] = (f32x2){U[1].x, U[1].y};
  } else if (tid >= 64 && tid < 64 + NQ) {
    const int j = tid - 64;
    const float* w = qp + g * 108 + 3 * j;
    float2 U0[4];
    fusedU(w[0], w[1], w[2], U0);
    float cx, sx;
    sincosf(x[s * NQ + j] * 0.5f, &sx, &cx);
    vq[j][0] = (f32x2){U0[0].x * cx + U0[1].x * sx, U0[0].y * cx + U0[1].y * sx};
    vq[j][1] = (f32x2){U0[2].x * cx + U0[3].x * sx, U0[2].y * cx + U0[3].y * sx};
  }
  __syncthreads();

  // product state (layer 0 folded): e = r*256+tid lives at (r*0x111) ^ tid ^ (tid>>4)
  {
    const unsigned bt = (unsigned)tid ^ ((unsigned)tid >> 4);
    f32x2 low = vq[11][tid & 1];
    #pragma unroll
    for (int p = 1; p < 8; ++p) low = pcmul(low, vq[11 - p][(tid >> p) & 1]);
    #pragma unroll
    for (int r = 0; r < 16; ++r) {
      f32x2 h = vq[3][r & 1];
      h = pcmul(h, vq[2][(r >> 1) & 1]);
      h = pcmul(h, vq[1][(r >> 2) & 1]);
      h = pcmul(h, vq[0][(r >> 3) & 1]);
      st[(r * 0x111) ^ bt] = pcmul(low, h);
    }
  }

  __syncthreads(); do_pass<0>(st, gAB, tid);
  __syncthreads(); do_pass<1>(st, gAB, tid);
  __syncthreads(); do_pass<2>(st, gAB, tid);
  __syncthreads(); do_pass<3>(st, gAB, tid);
  __syncthreads(); do_pass<4>(st, gAB, tid);
  __syncthreads(); do_pass<5>(st, gAB, tid);
  __syncthreads();

  // output gather with final ring^3 folded
  float* ob = out + (size_t)s * (NGEN * DIM) + (size_t)g * DIM;
  const unsigned lo = d_gtab.sflo[tid];
  #pragma unroll
  for (int k = 0; k < 16; ++k) {
    const f32x2 a = st[lo ^ d_gtab.sfhi[k]];
    ob[k * 256 + tid] = a.x * a.x + a.y * a.y;
  }
}

// ---------------- linear kernel: converted_x = (x @ W^T + b) * 5 ----------------
#define SPB 8
__global__ __launch_bounds__(256) void linear_kernel(const float* __restrict__ x,
                                                     const float* __restrict__ w,
                                                     const float* __restrict__ bb,
                                                     float* __restrict__ out2) {
  __shared__ float xs[SPB * NQ];
  const int tid = threadIdx.x;
  const int d0 = (blockIdx.x & 3) * 1024 + tid * 4;
  const int s0 = (blockIdx.x >> 2) * SPB;

  if (tid < SPB * NQ / 4)
    ((float4*)xs)[tid] = ((const float4*)(x + (size_t)s0 * NQ))[tid];

  float wr[4][NQ];
  float b4[4];
  #pragma unroll
  for (int dd = 0; dd < 4; ++dd) {
    #pragma unroll
    for (int jj = 0; jj < 3; ++jj)
      *(float4*)&wr[dd][jj * 4] = *(const float4*)&w[(size_t)(d0 + dd) * NQ + jj * 4];
    b4[dd] = bb[d0 + dd];
  }
  __syncthreads();

  #pragma unroll
  for (int s = 0; s < SPB; ++s) {
    float4 r;
    float* rp = &r.x;
    #pragma unroll
    for (int dd = 0; dd < 4; ++dd) {
      float acc = b4[dd];
      #pragma unroll
      for (int j = 0; j < NQ; ++j) acc = fmaf(xs[s * NQ + j], wr[dd][j], acc);
      rp[dd] = acc * 5.0f;
    }
    *(float4*)&out2[(size_t)(s0 + s) * DIM + d0] = r;
  }
}

extern "C" void kernel_launch(void* const* d_in, const int* in_sizes, int n_in,
                              void* d_out, int out_size, void* d_ws, size_t ws_size,
                              hipStream_t stream) {
  const float* x    = (const float*)d_in[0];
  const float* qp   = (const float*)d_in[1];
  const float* linw = (const float*)d_in[2];
  const float* linb = (const float*)d_in[3];
  float* out = (float*)d_out;

  qcirc_kernel<<<BATCH * NGEN, 256, 0, stream>>>(x, qp, out);
  linear_kernel<<<(BATCH / SPB) * 4, 256, 0, stream>>>(x, linw, linb,
                                                       out + (size_t)BATCH * NGEN * DIM);
}